// Round 14
// baseline (498.484 us; speedup 1.0000x reference)
//
#include <hip/hip_runtime.h>

#define NHOST 32768
#define MINF  65536
#define TSTEPS 365
#define DELTA_ 5
#define KMAX  6            // slots per (host,sublane); 4 sublanes -> supports cnt <= 24

// Constants from reference
#define C_E_STAR      0.032f
#define C_S_IMM       0.14f
#define C_S_INFTY     0.049f
#define C_X_H_STAR    97.3f
#define C_X_NU_STAR   4.8f
#define C_X_P_STAR    1514.4f
#define C_X_Y_STAR    3.5f
#define C_ALPHA_M     0.9f
#define C_ALPHA_M_ST  2.53f
#define C_GAMMA_P     2.04f
#define C_SIGMA_0     0.8124038404635961f  // sqrt(0.66)
#define C_LN2         0.6931471805599453f

// ---------------- host-placement permutation ----------------
// New host index hp -> old (offset-sorted) host o. Wave-chunk = 16 hosts.
// Block b, wave q gets chunk f(b,q) = b<256 ? 4b+q : 2047-4(b-256)-q.
// Blocks c and c+256 co-reside on a CU under round-robin dispatch; SIMD q
// then runs chunks 4c+q and 2047-4c-q whose iters sum to a constant ->
// per-SIMD load balance with per-wave work conserved and within-wave
// divergence unchanged (16 consecutive sorted ranks per wave).
__device__ __host__ inline int sigma_map(int hp) {
    int b = hp >> 6;
    int q = (hp >> 4) & 3;
    int l = hp & 15;
    int chunk = (b < 256) ? (4 * b + q) : (2047 - 4 * (b - 256) - q);
    return chunk * 16 + l;
}

// ---------------- preprocessing kernels ----------------

__global__ void initK(int* __restrict__ cnt, int* __restrict__ cursor) {
    int i = blockIdx.x * blockDim.x + threadIdx.x;
    if (i < NHOST) { cnt[i] = 0; cursor[i] = 0; }
}

__global__ void histK(const int* __restrict__ idx, int* __restrict__ cnt) {
    int j = blockIdx.x * blockDim.x + threadIdx.x;
    if (j < MINF) atomicAdd(&cnt[idx[j]], 1);
}

// Exclusive scan of cnt[NHOST] -> start[NHOST]; single block of 1024 threads.
__global__ __launch_bounds__(1024) void scanK(const int* __restrict__ cnt,
                                              int* __restrict__ start) {
    __shared__ int sh[1024];
    int tid = threadIdx.x;
    int base = tid * 32;
    int s = 0;
    #pragma unroll
    for (int k = 0; k < 32; ++k) s += cnt[base + k];
    sh[tid] = s;
    __syncthreads();
    for (int o = 1; o < 1024; o <<= 1) {
        int v = 0;
        if (tid >= o) v = sh[tid - o];
        __syncthreads();
        sh[tid] += v;
        __syncthreads();
    }
    int run = sh[tid] - s;
    #pragma unroll
    for (int k = 0; k < 32; ++k) {
        start[base + k] = run;
        run += cnt[base + k];
    }
}

__global__ void scatterK(const int* __restrict__ idx,
                         const float* __restrict__ tau0,
                         const float* __restrict__ tau_max,
                         const int* __restrict__ start,
                         int* __restrict__ cursor,
                         int* __restrict__ slotJ,
                         float* __restrict__ slotT0,
                         float* __restrict__ slotT1) {
    int j = blockIdx.x * blockDim.x + threadIdx.x;
    if (j >= MINF) return;
    int h = idx[j];
    int p = start[h] + atomicAdd(&cursor[h], 1);
    slotJ[p]  = j;
    slotT0[p] = tau0[j];
    slotT1[p] = tau_max[j];
}

// Gather per-host metadata into permuted order (mainK body stays untouched).
__global__ void permK(const int* __restrict__ offsets,
                      const float* __restrict__ log_d,
                      const int* __restrict__ start,
                      const int* __restrict__ cnt,
                      int* __restrict__ offsetsP,
                      float* __restrict__ log_dP,
                      int* __restrict__ startP,
                      int* __restrict__ cntP) {
    int hp = blockIdx.x * blockDim.x + threadIdx.x;
    if (hp >= NHOST) return;
    int o = sigma_map(hp);
    offsetsP[hp] = offsets[o];
    log_dP[hp]   = log_d[o];
    startP[hp]   = start[o];
    cntP[hp]     = cnt[o];
}

// Scatter Y/X_h from permuted scratch back to original host positions.
// X_y entries (outS[NHOST + j], j global infection index) copy straight.
__global__ void remapK(const float* __restrict__ outS, float* __restrict__ out) {
    int i = blockIdx.x * blockDim.x + threadIdx.x;
    if (i < NHOST) {
        int o = sigma_map(i);
        out[o] = outS[i];
        out[NHOST + MINF + o] = outS[NHOST + MINF + i];
    } else if (i < NHOST + MINF) {
        out[i] = outS[i];
    }
}

// ---------------- main kernel: BYTE-IDENTICAL body to round-6 (65 us) -------
// Lesson from r8/r9/r12/r13: this kernel sits on a register-allocation cliff
// (~36 live floats at VGPR 56); any body perturbation flips the allocator
// into a spill regime (VGPR drops to 36-48, VALU-cycles inflate 2.5-7x).
// Load-balance is therefore done entirely in the DATA (permK/remapK above);
// this body must compile exactly as in round 6. Signature check: VGPR == 56.

__global__ __launch_bounds__(256) void mainK(const float* __restrict__ EIR,
                                             const float* __restrict__ log_d,
                                             const int* __restrict__ offsets,
                                             const float* __restrict__ eps,
                                             const int* __restrict__ start,
                                             const int* __restrict__ cnt,
                                             const int* __restrict__ slotJ,
                                             const float* __restrict__ slotT0,
                                             const float* __restrict__ slotT1,
                                             float* __restrict__ out) {
    __shared__ float sEff[TSTEPS];
    __shared__ float sDm[TSTEPS];
    for (int k = threadIdx.x; k < TSTEPS; k += blockDim.x) {
        float tf  = (float)(k * DELTA_);
        float age = fminf(tf, 7300.0f) * (1.0f / 365.0f);
        float bs  = 2.009715297378839e-1f +
                    age * (1.7984405384216584e-1f +
                    age * (-2.121587990857579e-2f +
                    age * (1.3554013908681017e-3f +
                    age * (-2.847697353524861e-5f))));
        sEff[k] = EIR[k % 73] * bs * (1.0f / 1.63f);
        sDm[k]  = 1.0f - C_ALPHA_M * expf(-(tf / 365.0f / C_ALPHA_M_ST) * C_LN2);
    }
    __syncthreads();

    int tid = blockIdx.x * blockDim.x + threadIdx.x;
    int h   = tid >> 2;
    int sub = tid & 3;

    int off = offsets[h];
    int ch  = cnt[h];
    int myCnt = (ch > sub) ? ((ch - sub + 3) >> 2) : 0;
    if (myCnt > KMAX) myCnt = KMAX;          // P(cnt>24) ~ 1e-14: accept
    int base = start[h] + sub;
    float ld = log_d[h] + 1e-10f;            // log_d_inf + ln_yG (constant)

    int   J[KMAX];
    float T0[KMAX], T1[KMAX], Xy[KMAX], ec[KMAX];
    #pragma unroll
    for (int k = 0; k < KMAX; ++k) {
        Xy[k] = 0.0f; ec[k] = 0.0f; J[k] = 0;
        T0[k] = 1e30f; T1[k] = -1e30f;       // defaults -> never active
        if (k < myCnt) {
            int p = base + 4 * k;
            J[k]  = slotJ[p];
            T0[k] = slotT0[p];
            T1[k] = slotT1[p];
        }
    }

    int tstart = (off + DELTA_ - 1) / DELTA_;   // first t with t*DELTA >= off
    float Xp = 0.0f, Xh = 0.0f, Ylast = 0.0f;

    // prologue prefetch for t = tstart
    if (tstart < TSTEPS) {
        float tf0 = (float)(tstart * DELTA_);
        #pragma unroll
        for (int k = 0; k < KMAX; ++k)
            if (T0[k] <= tf0 && T1[k] > tf0)
                ec[k] = eps[(size_t)tstart * MINF + J[k]];
    }

    for (int t = tstart; t < TSTEPS; ++t) {
        float tf  = (float)(t * DELTA_);
        int   rel = t - tstart;                 // == clip((t*5-off)//5, 0, 364)
        float E   = sEff[rel];
        float Dm  = sDm[rel];

        // prefetch eps for t+1 (hides L3 latency under this iteration's VALU)
        float en[KMAX];
        #pragma unroll
        for (int k = 0; k < KMAX; ++k) en[k] = 0.0f;
        if (t < TSTEPS - 1) {
            float tf2 = tf + (float)DELTA_;
            #pragma unroll
            for (int k = 0; k < KMAX; ++k)
                if (T0[k] <= tf2 && T1[k] > tf2)
                    en[k] = eps[(size_t)(t + 1) * MINF + J[k]];
        }

        // host-state (computed redundantly by the quad's 4 lanes)
        float S1    = C_S_INFTY + (1.0f - C_S_INFTY) / (1.0f + E * (1.0f / C_E_STAR));
        float p204  = __powf(Xp * (1.0f / C_X_P_STAR), C_GAMMA_P);  // 0^2.04 -> 0
        float S2    = C_S_IMM + (1.0f - C_S_IMM) / (1.0f + p204);
        float hstar = S1 * S2 * E;
        float sigy  = C_SIGMA_0 * rsqrtf(1.0f + Xh * (1.0f / C_X_NU_STAR));
        float coef  = Dm / (1.0f + Xh * (1.0f / C_X_H_STAR));

        float ysum = 0.0f;
        float yk[KMAX];
        bool  ak[KMAX];
        #pragma unroll
        for (int k = 0; k < KMAX; ++k) {
            bool  act = (T0[k] <= tf) & (T1[k] > tf);
            float Dy  = 1.0f / (1.0f + Xy[k] * (1.0f / C_X_Y_STAR));
            float y   = act ? __expf(Dy * coef * ld + sigy * ec[k]) : 0.0f;
            ak[k] = act; yk[k] = y; ysum += y;
        }
        // quad (per-host) reduction
        float Ys = ysum + __shfl_xor(ysum, 1, 64);
        Ys += __shfl_xor(Ys, 2, 64);

        #pragma unroll
        for (int k = 0; k < KMAX; ++k)
            if (ak[k]) Xy[k] += Ys - yk[k];     // X_y += (Y - y) while active

        Xp += E; Xh += hstar; Ylast = Ys;

        #pragma unroll
        for (int k = 0; k < KMAX; ++k) ec[k] = en[k];
    }

    if (sub == 0) {
        out[h] = Ylast;                  // Y at final step
        out[NHOST + MINF + h] = Xh;      // X_h
    }
    #pragma unroll
    for (int k = 0; k < KMAX; ++k)
        if (k < myCnt) out[NHOST + J[k]] = Xy[k];   // X_y scattered to original j
}

// ---------------- launch ----------------

extern "C" void kernel_launch(void* const* d_in, const int* in_sizes, int n_in,
                              void* d_out, int out_size, void* d_ws, size_t ws_size,
                              hipStream_t stream) {
    const float* EIR     = (const float*)d_in[0];
    const float* log_d   = (const float*)d_in[1];
    const float* tau0    = (const float*)d_in[2];
    const float* tau_max = (const float*)d_in[3];
    const float* eps     = (const float*)d_in[4];
    const int*   idx     = (const int*)d_in[5];
    const int*   offsets = (const int*)d_in[6];
    float* out = (float*)d_out;

    char* ws = (char*)d_ws;
    int*   cnt      = (int*)ws;    ws += NHOST * sizeof(int);
    int*   start    = (int*)ws;    ws += NHOST * sizeof(int);
    int*   cursor   = (int*)ws;    ws += NHOST * sizeof(int);
    int*   slotJ    = (int*)ws;    ws += MINF * sizeof(int);
    float* slotT0   = (float*)ws;  ws += MINF * sizeof(float);
    float* slotT1   = (float*)ws;  ws += MINF * sizeof(float);
    int*   offsetsP = (int*)ws;    ws += NHOST * sizeof(int);
    float* log_dP   = (float*)ws;  ws += NHOST * sizeof(float);
    int*   startP   = (int*)ws;    ws += NHOST * sizeof(int);
    int*   cntP     = (int*)ws;    ws += NHOST * sizeof(int);
    float* outS     = (float*)ws;  ws += (NHOST + MINF + NHOST) * sizeof(float);

    initK<<<NHOST / 256, 256, 0, stream>>>(cnt, cursor);
    histK<<<MINF / 256, 256, 0, stream>>>(idx, cnt);
    scanK<<<1, 1024, 0, stream>>>(cnt, start);
    scatterK<<<MINF / 256, 256, 0, stream>>>(idx, tau0, tau_max, start, cursor,
                                             slotJ, slotT0, slotT1);
    permK<<<NHOST / 256, 256, 0, stream>>>(offsets, log_d, start, cnt,
                                           offsetsP, log_dP, startP, cntP);
    mainK<<<(NHOST * 4) / 256, 256, 0, stream>>>(EIR, log_dP, offsetsP, eps,
                                                 startP, cntP, slotJ, slotT0, slotT1,
                                                 outS);
    remapK<<<(NHOST + MINF) / 256, 256, 0, stream>>>(outS, out);
}